// Round 1
// baseline (133.268 us; speedup 1.0000x reference)
//
#include <hip/hip_runtime.h>

// Problem: hidden = tanh(x @ (Wi+Wh)^T + (bi+bh)); h_last = hidden[:, T-1, :]
// x: (B,T,C) fp32; Wi,Wh: (H,C) fp32. B=16,T=4096,C=H=256.
// GEMM: M=65536, N=256, K=256. Memory-bound (~130MB traffic -> ~21us floor).
//
// v2 structure: B (weights) entirely in registers per wave (16 cols x K=256
// = 32 VGPRs), K fully unrolled. x streamed through 2x16KB double-buffered
// LDS with register prefetch; ONE barrier per 32-row tile. 16 waves/CU
// (50% occupancy), 256 persistent blocks x 8 grid-stride tiles.

using short8 = __attribute__((ext_vector_type(8))) short;
using f32x4  = __attribute__((ext_vector_type(4))) float;

constexpr int Bn = 16, Tn = 4096, Cn = 256, Hn = 256;
constexpr int Mn    = Bn * Tn;       // 65536
constexpr int BM    = 32;            // rows per tile
constexpr int NBLK  = 256;           // 1 block per CU
constexpr int TILES = Mn / BM;       // 2048
constexpr int ITERS = TILES / NBLK;  // 8

// round-to-nearest-even fp32 -> bf16, two at a time, packed into one u32
__device__ inline unsigned pack2_bf16(float a, float b) {
  unsigned ua = __float_as_uint(a);
  unsigned ub = __float_as_uint(b);
  ua += 0x7fffu + ((ua >> 16) & 1u);
  ub += 0x7fffu + ((ub >> 16) & 1u);
  return (ua >> 16) | (ub & 0xffff0000u);
}

__global__ __launch_bounds__(256) void prep_kernel(
    const float* __restrict__ Wi, const float* __restrict__ bi,
    const float* __restrict__ Wh, const float* __restrict__ bh,
    unsigned short* __restrict__ Wc, float* __restrict__ bc) {
  int idx = blockIdx.x * 256 + threadIdx.x;
  float w = Wi[idx] + Wh[idx];
  unsigned u = __float_as_uint(w);
  u += 0x7fffu + ((u >> 16) & 1u);
  Wc[idx] = (unsigned short)(u >> 16);
  if (blockIdx.x == 0) bc[threadIdx.x] = bi[threadIdx.x] + bh[threadIdx.x];
}

// 1024 threads = 16 waves; wave w owns output cols [16w, 16w+16) with its
// B fragments (full K) resident in registers. All waves share the 32-row
// x tile staged in LDS (bf16, XOR-swizzled 16B chunks -> conflict-uniform).
__global__ __launch_bounds__(1024, 4) void gemm_tanh_kernel(
    const float* __restrict__ x, const unsigned short* __restrict__ Wc,
    const float* __restrict__ bc, float* __restrict__ out) {
  __shared__ __align__(16) unsigned short Asm[2][BM * Cn];  // 2 x 16 KB

  const int tid  = threadIdx.x;
  const int lane = tid & 63;
  const int wave = tid >> 6;        // 0..15
  const int rid  = lane & 15;       // row (A) / col (B) within 16x16 tile
  const int kgrp = lane >> 4;       // 0..3: k-group of 8
  const int col  = wave * 16 + rid; // output column owned by this lane

  // ---- B fragments for full K=256: 8 x short8 = 32 VGPRs, loaded once.
  short8 bf[8];
#pragma unroll
  for (int ks = 0; ks < 8; ks++)
    bf[ks] = *(const short8*)&Wc[col * Cn + ks * 32 + kgrp * 8];
  const float bias = bc[col];

  // staging role: thread -> (row sr, 16B-chunk sc) of the 32x256 tile
  const int sr  = tid >> 5;                  // 0..31
  const int sc  = tid & 31;                  // 0..31
  const int swz = ((sc ^ (sr & 7)) << 3);    // swizzled short index in row

  f32x4 acc[2];
  acc[0] = (f32x4)0.f;
  acc[1] = (f32x4)0.f;

  float4 v0, v1;

  // ---- prologue: tile 0 -> LDS buf 0
  {
    const float4* src =
        (const float4*)(x + (size_t)(blockIdx.x * BM + sr) * Cn + sc * 8);
    v0 = src[0];
    v1 = src[1];
    uint4 p;
    p.x = pack2_bf16(v0.x, v0.y);
    p.y = pack2_bf16(v0.z, v0.w);
    p.z = pack2_bf16(v1.x, v1.y);
    p.w = pack2_bf16(v1.z, v1.w);
    *(uint4*)&Asm[0][sr * Cn + swz] = p;
  }
  __syncthreads();

  for (int t = 0; t < ITERS; t++) {
    const int cur = t & 1;
    const int m0  = (blockIdx.x + t * NBLK) * BM;

    // ---- prefetch tile t+1 into registers (consumed after MFMA phase,
    // so HBM latency hides under the compute below)
    if (t + 1 < ITERS) {
      const float4* src =
          (const float4*)(x + (size_t)(m0 + NBLK * BM + sr) * Cn + sc * 8);
      v0 = src[0];
      v1 = src[1];
    }

    // ---- MFMA phase: full K unrolled, B from registers
#pragma unroll
    for (int ks = 0; ks < 8; ks++) {
#pragma unroll
      for (int mt = 0; mt < 2; mt++) {
        int row = mt * 16 + rid;
        short8 a = *(const short8*)
            &Asm[cur][row * Cn + ((((ks << 2) | kgrp) ^ (rid & 7)) << 3)];
        acc[mt] = __builtin_amdgcn_mfma_f32_16x16x32_bf16(a, bf[ks], acc[mt],
                                                          0, 0, 0);
      }
    }

    // ---- write tile t+1 into the other buffer (waits only on v0/v1)
    if (t + 1 < ITERS) {
      uint4 p;
      p.x = pack2_bf16(v0.x, v0.y);
      p.y = pack2_bf16(v0.z, v0.w);
      p.z = pack2_bf16(v1.x, v1.y);
      p.w = pack2_bf16(v1.z, v1.w);
      *(uint4*)&Asm[cur ^ 1][sr * Cn + swz] = p;
    }

    // ---- epilogue: bias + tanh, store (only vmem outstanding at barrier)
#pragma unroll
    for (int mt = 0; mt < 2; mt++) {
#pragma unroll
      for (int r = 0; r < 4; r++) {
        int m   = m0 + mt * 16 + kgrp * 4 + r;
        float v = acc[mt][r] + bias;
        // tanh(v) = 1 - 2/(exp(2v)+1); overflow -> 1, underflow -> -1
        float tv = 1.f - 2.f / (__expf(2.f * v) + 1.f);
        out[(size_t)m * Hn + col] = tv;
        if ((m & (Tn - 1)) == (Tn - 1))
          out[(size_t)Mn * Hn + (size_t)(m >> 12) * Hn + col] = tv;
      }
      acc[mt] = (f32x4)0.f;
    }

    if (t + 1 < ITERS) __syncthreads();
  }
}

extern "C" void kernel_launch(void* const* d_in, const int* in_sizes, int n_in,
                              void* d_out, int out_size, void* d_ws,
                              size_t ws_size, hipStream_t stream) {
  (void)in_sizes; (void)n_in; (void)out_size; (void)ws_size;
  const float* x  = (const float*)d_in[0];
  const float* Wi = (const float*)d_in[1];
  const float* bi = (const float*)d_in[2];
  const float* Wh = (const float*)d_in[3];
  const float* bh = (const float*)d_in[4];
  float* out = (float*)d_out;

  unsigned short* Wc = (unsigned short*)d_ws;  // 128 KB bf16
  float* bc = (float*)((char*)d_ws + (size_t)Hn * Cn * sizeof(unsigned short));

  prep_kernel<<<(Hn * Cn) / 256, 256, 0, stream>>>(Wi, bi, Wh, bh, Wc, bc);
  gemm_tanh_kernel<<<NBLK, 1024, 0, stream>>>(x, Wc, bc, out);
}